// Round 1
// baseline (363.544 us; speedup 1.0000x reference)
//
#include <hip/hip_runtime.h>
#include <hip/hip_bf16.h>

// MMD loss: source/target 4096x256 fp32, output = scalar fp32.
// N = 8192 total rows, D = 256.
//
// ws layout (bytes):
//   [0 .. 4096)   : doubles d[0]=sum_sq, d[1..256]=colsum, d[257]=acc, d[258]=neg_gamma
//   [4096 .. 36864): float sq[8192]
#define WS_D_SUMSQ   0
#define WS_D_COLSUM  1
#define WS_D_ACC     257
#define WS_D_NEGG    258
#define WS_SQ_BYTES  4096

#define NROW 8192
#define HALF 4096
#define DIM  256
#define TILE 128
#define NB   64      // 8192/128
#define TKC  32      // K-chunk staged in LDS

// ---------- kernel A: per-row sum of squares + global sum_sq (double) ----------
__global__ __launch_bounds__(256) void k_sq(const float* __restrict__ src,
                                            const float* __restrict__ tgt,
                                            float* __restrict__ sq,
                                            double* __restrict__ sum_sq) {
    int row  = blockIdx.x * 4 + (threadIdx.x >> 6);
    int lane = threadIdx.x & 63;
    const float* base = (row < HALF) ? (src + (size_t)row * DIM)
                                     : (tgt + (size_t)(row - HALF) * DIM);
    float4 v = *(const float4*)(base + lane * 4);
    float s = v.x * v.x + v.y * v.y + v.z * v.z + v.w * v.w;
    #pragma unroll
    for (int off = 32; off; off >>= 1) s += __shfl_down(s, off);
    if (lane == 0) {
        sq[row] = s;
        atomicAdd(sum_sq, (double)s);
    }
}

// ---------- kernel B: column sums (double) ----------
__global__ __launch_bounds__(256) void k_colsum(const float* __restrict__ src,
                                                const float* __restrict__ tgt,
                                                double* __restrict__ colsum) {
    int t  = threadIdx.x;          // column 0..255
    int r0 = blockIdx.x * 128;     // 64 blocks x 128 rows
    double s = 0.0;
    for (int r = r0; r < r0 + 128; ++r) {
        const float* base = (r < HALF) ? (src + (size_t)r * DIM)
                                       : (tgt + (size_t)(r - HALF) * DIM);
        s += (double)base[t];
    }
    atomicAdd(&colsum[t], s);
}

// ---------- kernel C: bandwidth -> neg_gamma = -1/(16*bw) ----------
__global__ __launch_bounds__(256) void k_bw(double* __restrict__ wsd) {
    __shared__ double red[256];
    int t = threadIdx.x;
    double c = wsd[WS_D_COLSUM + t];
    red[t] = c * c;
    __syncthreads();
    for (int off = 128; off; off >>= 1) {
        if (t < off) red[t] += red[t + off];
        __syncthreads();
    }
    if (t == 0) {
        const double N = (double)NROW;
        double sum_l2 = 2.0 * N * wsd[WS_D_SUMSQ] - 2.0 * red[0];
        double bw = sum_l2 / (N * N - N);
        bw = bw / 4.0;  // KERNEL_MUL ** (KERNEL_NUM//2) = 2^2
        wsd[WS_D_NEGG] = -1.0 / (16.0 * bw);
    }
}

// ---------- kernel D: main pairwise pass (upper-triangular block tiles) ----------
__global__ __launch_bounds__(256) void k_mmd(const float* __restrict__ src,
                                             const float* __restrict__ tgt,
                                             const float* __restrict__ sq,
                                             const double* __restrict__ wsd,
                                             double* __restrict__ acc_out) {
    __shared__ float As[TKC][TILE];  // transposed: [k][row], 16 KB
    __shared__ float Bs[TKC][TILE];

    // decode linear block id -> (bi, bj) with bi <= bj
    int bid = blockIdx.x;
    int bi = 0, rem = bid;
    while (rem >= NB - bi) { rem -= NB - bi; ++bi; }
    int bj = bi + rem;

    const float* abase = (bi < 32) ? (src + (size_t)bi * TILE * DIM)
                                   : (tgt + (size_t)(bi - 32) * TILE * DIM);
    const float* bbase = (bj < 32) ? (src + (size_t)bj * TILE * DIM)
                                   : (tgt + (size_t)(bj - 32) * TILE * DIM);

    int t  = threadIdx.x;
    int tx = t & 15, ty = t >> 4;
    int sr = t >> 1;        // staging row 0..127 (2 threads per row)
    int sp = t & 1;         // staging parity

    float acc[8][8];
    #pragma unroll
    for (int i = 0; i < 8; ++i)
        #pragma unroll
        for (int j = 0; j < 8; ++j) acc[i][j] = 0.0f;

    for (int kc = 0; kc < DIM / TKC; ++kc) {
        __syncthreads();
        const float* ap = abase + (size_t)sr * DIM + kc * TKC;
        const float* bp = bbase + (size_t)sr * DIM + kc * TKC;
        #pragma unroll
        for (int it = 0; it < 4; ++it) {
            int cg = sp + it * 2;  // float4 group 0..7 within the 32-col chunk
            float4 va = *(const float4*)(ap + cg * 4);
            As[cg * 4 + 0][sr] = va.x;
            As[cg * 4 + 1][sr] = va.y;
            As[cg * 4 + 2][sr] = va.z;
            As[cg * 4 + 3][sr] = va.w;
            float4 vb = *(const float4*)(bp + cg * 4);
            Bs[cg * 4 + 0][sr] = vb.x;
            Bs[cg * 4 + 1][sr] = vb.y;
            Bs[cg * 4 + 2][sr] = vb.z;
            Bs[cg * 4 + 3][sr] = vb.w;
        }
        __syncthreads();

        #pragma unroll 8
        for (int k = 0; k < TKC; ++k) {
            float av[8], bv[8];
            *(float4*)&av[0] = *(const float4*)&As[k][ty * 8];
            *(float4*)&av[4] = *(const float4*)&As[k][ty * 8 + 4];
            *(float4*)&bv[0] = *(const float4*)&Bs[k][tx * 8];
            *(float4*)&bv[4] = *(const float4*)&Bs[k][tx * 8 + 4];
            #pragma unroll
            for (int ii = 0; ii < 8; ++ii)
                #pragma unroll
                for (int jj = 0; jj < 8; ++jj)
                    acc[ii][jj] = fmaf(av[ii], bv[jj], acc[ii][jj]);
        }
    }

    // epilogue: l2 -> 5-kernel sum via exp-squaring chain, signed double accumulate
    int gi0 = bi * TILE + ty * 8;
    int gj0 = bj * TILE + tx * 8;
    float sqa[8], sqb[8];
    #pragma unroll
    for (int i = 0; i < 8; ++i) { sqa[i] = sq[gi0 + i]; sqb[i] = sq[gj0 + i]; }
    float ng = (float)wsd[WS_D_NEGG];

    double tsum = 0.0;
    #pragma unroll
    for (int ii = 0; ii < 8; ++ii) {
        #pragma unroll
        for (int jj = 0; jj < 8; ++jj) {
            float l2 = fmaxf(sqa[ii] + sqb[jj] - 2.0f * acc[ii][jj], 0.0f);
            float e  = expf(l2 * ng);          // exp(-l2/(16 bw))  == kernel i=4
            float e2 = e * e;                  // i=3
            float e4 = e2 * e2;                // i=2
            float e8 = e4 * e4;                // i=1
            float e16 = e8 * e8;               // i=0
            tsum += (double)(e + e2 + e4 + e8 + e16);
        }
    }

    double w = ((bi < 32) == (bj < 32)) ? 1.0 : -1.0;
    if (bi != bj) w += w;  // off-diagonal tiles count twice (symmetry)
    tsum *= w;

    #pragma unroll
    for (int off = 32; off; off >>= 1) tsum += __shfl_down(tsum, off);
    if ((t & 63) == 0) atomicAdd(acc_out, tsum);
}

// ---------- kernel E: finalize ----------
__global__ void k_final(const double* __restrict__ wsd, float* __restrict__ out) {
    out[0] = (float)(wsd[WS_D_ACC] / ((double)HALF * (double)HALF));
}

extern "C" void kernel_launch(void* const* d_in, const int* in_sizes, int n_in,
                              void* d_out, int out_size, void* d_ws, size_t ws_size,
                              hipStream_t stream) {
    const float* src = (const float*)d_in[0];
    const float* tgt = (const float*)d_in[1];
    float* out = (float*)d_out;

    double* wsd = (double*)d_ws;
    float*  sq  = (float*)((char*)d_ws + WS_SQ_BYTES);

    // zero the double accumulators (sum_sq, colsum, acc) every launch
    hipMemsetAsync(d_ws, 0, WS_SQ_BYTES, stream);

    k_sq<<<NROW / 4, 256, 0, stream>>>(src, tgt, sq, &wsd[WS_D_SUMSQ]);
    k_colsum<<<NROW / 128, 256, 0, stream>>>(src, tgt, &wsd[WS_D_COLSUM]);
    k_bw<<<1, 256, 0, stream>>>(wsd);

    int nblocks = NB * (NB + 1) / 2;  // 2080 upper-triangular tiles
    k_mmd<<<nblocks, 256, 0, stream>>>(src, tgt, sq, wsd, &wsd[WS_D_ACC]);

    k_final<<<1, 1, 0, stream>>>(wsd, out);
}

// Round 2
// 177.443 us; speedup vs baseline: 2.0488x; 2.0488x over previous
//
#include <hip/hip_runtime.h>
#include <hip/hip_bf16.h>

// MMD loss: source/target 4096x256 fp32, output = scalar fp32.
// N = 8192 total rows, D = 256. Gram pass in bf16 MFMA (error analysis: the
// bf16 perturbation is statistically identical across the four quadrants of
// xx+yy-xy-yx and cancels; diagonal kept exact by computing sq[] from the
// SAME bf16-rounded values the MFMA consumes).
//
// ws layout: doubles d[0]=sum_sq, d[1..256]=colsum, d[257]=neg_gamma,
//            d[258..289]=acc slots (32); floats sq[8192] at byte 4096.
#define WS_D_SUMSQ  0
#define WS_D_COLSUM 1
#define WS_D_NEGG   257
#define WS_D_ACC    258
#define WS_ACC_SLOTS 32
#define WS_SQ_BYTES 4096

#define NROW 8192
#define HALF 4096
#define DIM  256
#define TILE 128
#define NB   64      // 8192/128

typedef short short8 __attribute__((ext_vector_type(8)));
typedef float f32x4  __attribute__((ext_vector_type(4)));

static __device__ __forceinline__ short f2bf(float f) {
    __hip_bfloat16 h = __float2bfloat16(f);   // RNE
    return *reinterpret_cast<short*>(&h);
}
static __device__ __forceinline__ float bfround(float f) {
    return __bfloat162float(__float2bfloat16(f));
}

// ---------- kernel A: per-row sum of squares of bf16-rounded rows ----------
__global__ __launch_bounds__(256) void k_sq(const float* __restrict__ src,
                                            const float* __restrict__ tgt,
                                            float* __restrict__ sq,
                                            double* __restrict__ sum_sq) {
    int row  = blockIdx.x * 4 + (threadIdx.x >> 6);
    int lane = threadIdx.x & 63;
    const float* base = (row < HALF) ? (src + (size_t)row * DIM)
                                     : (tgt + (size_t)(row - HALF) * DIM);
    float4 v = *(const float4*)(base + lane * 4);
    float x0 = bfround(v.x), x1 = bfround(v.y), x2 = bfround(v.z), x3 = bfround(v.w);
    float s = x0 * x0 + x1 * x1 + x2 * x2 + x3 * x3;
    #pragma unroll
    for (int off = 32; off; off >>= 1) s += __shfl_down(s, off);
    if (lane == 0) {
        sq[row] = s;
        atomicAdd(sum_sq, (double)s);
    }
}

// ---------- kernel B: column sums (for analytic sum(l2)) ----------
__global__ __launch_bounds__(256) void k_colsum(const float* __restrict__ src,
                                                const float* __restrict__ tgt,
                                                double* __restrict__ colsum) {
    int t  = threadIdx.x;          // column 0..255
    int r0 = blockIdx.x * 32;      // 256 blocks x 32 rows
    double s = 0.0;
    for (int r = r0; r < r0 + 32; ++r) {
        const float* base = (r < HALF) ? (src + (size_t)r * DIM)
                                       : (tgt + (size_t)(r - HALF) * DIM);
        s += (double)bfround(base[t]);
    }
    atomicAdd(&colsum[t], s);
}

// ---------- kernel C: bandwidth -> neg_gamma = -1/(16*bw) ----------
__global__ __launch_bounds__(256) void k_bw(double* __restrict__ wsd) {
    __shared__ double red[256];
    int t = threadIdx.x;
    double c = wsd[WS_D_COLSUM + t];
    red[t] = c * c;
    __syncthreads();
    for (int off = 128; off; off >>= 1) {
        if (t < off) red[t] += red[t + off];
        __syncthreads();
    }
    if (t == 0) {
        const double N = (double)NROW;
        double sum_l2 = 2.0 * N * wsd[WS_D_SUMSQ] - 2.0 * red[0];
        double bw = sum_l2 / (N * N - N);
        bw = bw / 4.0;  // KERNEL_MUL ** (KERNEL_NUM//2) = 2^2
        wsd[WS_D_NEGG] = -1.0 / (16.0 * bw);
    }
}

// ---------- kernel D: MFMA pairwise pass (upper-triangular block tiles) ----------
// LDS layout: [row][k] bf16, k-chunk of 32 (4 slots of 8 bf16 = 16B).
// XOR swizzle slot' = slot ^ ((row>>1)&3): each 16-lane b128 group covers all
// 8 bank-quads exactly twice (2-way = free).
__global__ __launch_bounds__(256) void k_mmd(const float* __restrict__ src,
                                             const float* __restrict__ tgt,
                                             const float* __restrict__ sq,
                                             const double* __restrict__ wsd,
                                             double* __restrict__ acc_slots) {
    __shared__ short As[TILE * 32];   // 8 KB
    __shared__ short Bs[TILE * 32];   // 8 KB
    __shared__ double wsum[4];

    // decode linear block id -> (bi, bj) with bi <= bj
    int bi = 0, rem = blockIdx.x;
    while (rem >= NB - bi) { rem -= NB - bi; ++bi; }
    int bj = bi + rem;

    const float* abase = (bi < 32) ? (src + (size_t)bi * TILE * DIM)
                                   : (tgt + (size_t)(bi - 32) * TILE * DIM);
    const float* bbase = (bj < 32) ? (src + (size_t)bj * TILE * DIM)
                                   : (tgt + (size_t)(bj - 32) * TILE * DIM);

    int t    = threadIdx.x;
    int wid  = t >> 6;
    int lane = t & 63;
    int wr   = wid >> 1;      // wave row 0..1 (64-row strip)
    int wc   = wid & 1;       // wave col 0..1 (64-col strip)
    int srow  = t >> 1;       // staging row 0..127
    int shalf = t & 1;        // which 16-float half of the 32-float k-chunk

    const f32x4 zero4 = {0.f, 0.f, 0.f, 0.f};
    f32x4 acc[4][4];
    #pragma unroll
    for (int i = 0; i < 4; ++i)
        #pragma unroll
        for (int j = 0; j < 4; ++j) acc[i][j] = zero4;

    int klane = lane >> 4;    // k-slot 0..3 for MFMA fragment
    int rl    = lane & 15;

    for (int kc = 0; kc < DIM / 32; ++kc) {
        // issue global loads early (before the barrier) so HBM/L2 latency
        // hides under the previous chunk's MFMAs
        const float4* ap4 = (const float4*)(abase + (size_t)srow * DIM + kc * 32 + shalf * 16);
        const float4* bp4 = (const float4*)(bbase + (size_t)srow * DIM + kc * 32 + shalf * 16);
        float4 va0 = ap4[0], va1 = ap4[1], va2 = ap4[2], va3 = ap4[3];
        float4 vb0 = bp4[0], vb1 = bp4[1], vb2 = bp4[2], vb3 = bp4[3];

        __syncthreads();  // previous chunk's LDS reads done

        short ta[16], tb[16];
        ta[0]=f2bf(va0.x); ta[1]=f2bf(va0.y); ta[2]=f2bf(va0.z); ta[3]=f2bf(va0.w);
        ta[4]=f2bf(va1.x); ta[5]=f2bf(va1.y); ta[6]=f2bf(va1.z); ta[7]=f2bf(va1.w);
        ta[8]=f2bf(va2.x); ta[9]=f2bf(va2.y); ta[10]=f2bf(va2.z); ta[11]=f2bf(va2.w);
        ta[12]=f2bf(va3.x); ta[13]=f2bf(va3.y); ta[14]=f2bf(va3.z); ta[15]=f2bf(va3.w);
        tb[0]=f2bf(vb0.x); tb[1]=f2bf(vb0.y); tb[2]=f2bf(vb0.z); tb[3]=f2bf(vb0.w);
        tb[4]=f2bf(vb1.x); tb[5]=f2bf(vb1.y); tb[6]=f2bf(vb1.z); tb[7]=f2bf(vb1.w);
        tb[8]=f2bf(vb2.x); tb[9]=f2bf(vb2.y); tb[10]=f2bf(vb2.z); tb[11]=f2bf(vb2.w);
        tb[12]=f2bf(vb3.x); tb[13]=f2bf(vb3.y); tb[14]=f2bf(vb3.z); tb[15]=f2bf(vb3.w);

        int sw = (srow >> 1) & 3;
        int s0 = (2 * shalf) ^ sw;
        int s1 = (2 * shalf + 1) ^ sw;
        *(short8*)&As[srow * 32 + s0 * 8] = *(short8*)&ta[0];
        *(short8*)&As[srow * 32 + s1 * 8] = *(short8*)&ta[8];
        *(short8*)&Bs[srow * 32 + s0 * 8] = *(short8*)&tb[0];
        *(short8*)&Bs[srow * 32 + s1 * 8] = *(short8*)&tb[8];

        __syncthreads();  // chunk staged

        short8 af[4], bfr[4];
        #pragma unroll
        for (int f = 0; f < 4; ++f) {
            int ra = wr * 64 + f * 16 + rl;
            af[f]  = *(const short8*)&As[ra * 32 + (klane ^ ((ra >> 1) & 3)) * 8];
            int rb = wc * 64 + f * 16 + rl;
            bfr[f] = *(const short8*)&Bs[rb * 32 + (klane ^ ((rb >> 1) & 3)) * 8];
        }
        #pragma unroll
        for (int i = 0; i < 4; ++i)
            #pragma unroll
            for (int j = 0; j < 4; ++j)
                acc[i][j] = __builtin_amdgcn_mfma_f32_16x16x32_bf16(af[i], bfr[j], acc[i][j], 0, 0, 0);
    }

    // epilogue: l2 -> 5-kernel sum via exp-squaring chain
    // C/D layout (m89): col = lane&15, row = (lane>>4)*4 + reg
    int gi0 = bi * TILE + wr * 64;
    int gj0 = bj * TILE + wc * 64;
    float ng = (float)wsd[WS_D_NEGG];
    int rgrp = lane >> 4;

    float sqb4[4];
    #pragma unroll
    for (int j = 0; j < 4; ++j) sqb4[j] = sq[gj0 + j * 16 + rl];

    float tsum = 0.f;
    #pragma unroll
    for (int i = 0; i < 4; ++i) {
        float sqa4[4];
        #pragma unroll
        for (int rr = 0; rr < 4; ++rr) sqa4[rr] = sq[gi0 + i * 16 + rgrp * 4 + rr];
        #pragma unroll
        for (int j = 0; j < 4; ++j) {
            #pragma unroll
            for (int rr = 0; rr < 4; ++rr) {
                float l2 = fmaxf(sqa4[rr] + sqb4[j] - 2.0f * acc[i][j][rr], 0.f);
                float e   = __expf(l2 * ng);   // exp(-l2/(16 bw)) == kernel i=4
                float e2  = e * e;             // i=3
                float e4  = e2 * e2;           // i=2
                float e8  = e4 * e4;           // i=1
                float e16 = e8 * e8;           // i=0
                tsum += e + e2 + e4 + e8 + e16;
            }
        }
    }

    float w = ((bi < 32) == (bj < 32)) ? 1.f : -1.f;
    if (bi != bj) w *= 2.f;   // off-diagonal tiles count twice (symmetry)
    double dsum = (double)tsum * (double)w;

    #pragma unroll
    for (int off = 32; off; off >>= 1) dsum += __shfl_down(dsum, off);
    if (lane == 0) wsum[wid] = dsum;
    __syncthreads();
    if (t == 0)
        atomicAdd(&acc_slots[blockIdx.x & (WS_ACC_SLOTS - 1)],
                  wsum[0] + wsum[1] + wsum[2] + wsum[3]);
}

// ---------- kernel E: finalize ----------
__global__ void k_final(const double* __restrict__ wsd, float* __restrict__ out) {
    double s = 0.0;
    for (int i = 0; i < WS_ACC_SLOTS; ++i) s += wsd[WS_D_ACC + i];
    out[0] = (float)(s / ((double)HALF * (double)HALF));
}

extern "C" void kernel_launch(void* const* d_in, const int* in_sizes, int n_in,
                              void* d_out, int out_size, void* d_ws, size_t ws_size,
                              hipStream_t stream) {
    const float* src = (const float*)d_in[0];
    const float* tgt = (const float*)d_in[1];
    float* out = (float*)d_out;

    double* wsd = (double*)d_ws;
    float*  sq  = (float*)((char*)d_ws + WS_SQ_BYTES);

    // zero the double accumulators (sum_sq, colsum, acc slots) every launch
    hipMemsetAsync(d_ws, 0, WS_SQ_BYTES, stream);

    k_sq<<<NROW / 4, 256, 0, stream>>>(src, tgt, sq, &wsd[WS_D_SUMSQ]);
    k_colsum<<<NROW / 32, 256, 0, stream>>>(src, tgt, &wsd[WS_D_COLSUM]);
    k_bw<<<1, 256, 0, stream>>>(wsd);

    int nblocks = NB * (NB + 1) / 2;  // 2080 upper-triangular tiles
    k_mmd<<<nblocks, 256, 0, stream>>>(src, tgt, sq, wsd, &wsd[WS_D_ACC]);

    k_final<<<1, 1, 0, stream>>>(wsd, out);
}

// Round 3
// 73.799 us; speedup vs baseline: 4.9262x; 2.4044x over previous
//
#include <hip/hip_runtime.h>
#include <hip/hip_bf16.h>

// MMD loss: source/target 4096x256 fp32, output = scalar fp32.
// N = 8192 rows, D = 256. Pipeline:
//   k_cvt    : fp32 -> bf16 matrix G (4 MB in ws) + per-row sq[] (fp32, from the
//              SAME bf16-rounded values -> diagonal stays exact). No atomics.
//   k_colsum : column sums of G (double, 64-deep atomics per address).
//   k_bw     : reduce sq[] (double) + colsum^2 -> neg_gamma2 = -log2(e)/(16*bw).
//   k_mmd    : bf16 MFMA Gram pass over upper-triangular 128x128 tiles,
//              global_load_lds staging (no VALU), XOR-swizzled LDS
//              (linear dest + inverse-swizzled source + swizzled read).
//   k_final  : scale.
//
// ws layout: doubles d[0..255]=colsum, d[256]=neg_gamma2, d[257..288]=acc slots;
//            float sq[8192] at byte 4096; bf16 G[8192*256] at byte 36864.
#define WS_D_COLSUM 0
#define WS_D_NEGG   256
#define WS_D_ACC    257
#define WS_ACC_SLOTS 32
#define WS_SQ_OFF   4096
#define WS_G_OFF    36864

#define NROW 8192
#define HALF 4096
#define DIM  256
#define TILE 128
#define NB   64      // 8192/128
#define KC   64      // k-chunk (bf16 elems, 128 B/row)
#define NC   (DIM / KC)

typedef short  short8  __attribute__((ext_vector_type(8)));
typedef float  f32x4   __attribute__((ext_vector_type(4)));
typedef unsigned short us4 __attribute__((ext_vector_type(4)));

static __device__ __forceinline__ unsigned short f2bfbits(float f) {
    __hip_bfloat16 h = __float2bfloat16(f);   // RNE
    return *reinterpret_cast<unsigned short*>(&h);
}
static __device__ __forceinline__ float bfbits2f(unsigned short u) {
    return __uint_as_float(((unsigned int)u) << 16);
}
static __device__ __forceinline__ void gl_lds16(const void* g, void* l) {
    __builtin_amdgcn_global_load_lds(
        (const __attribute__((address_space(1))) void*)g,
        (__attribute__((address_space(3))) void*)l, 16, 0, 0);
}

// ---------- kernel A: convert to bf16 + per-row sum of squares (no atomics) ----
__global__ __launch_bounds__(256) void k_cvt(const float* __restrict__ src,
                                             const float* __restrict__ tgt,
                                             unsigned short* __restrict__ G,
                                             float* __restrict__ sq) {
    int t    = threadIdx.x;
    int row  = blockIdx.x * 4 + (t >> 6);
    int lane = t & 63;
    const float* base = (row < HALF) ? (src + (size_t)row * DIM)
                                     : (tgt + (size_t)(row - HALF) * DIM);
    float4 v = *(const float4*)(base + lane * 4);
    unsigned short u0 = f2bfbits(v.x), u1 = f2bfbits(v.y),
                   u2 = f2bfbits(v.z), u3 = f2bfbits(v.w);
    us4 uu = {u0, u1, u2, u3};
    *(us4*)(G + (size_t)row * DIM + lane * 4) = uu;
    float r0 = bfbits2f(u0), r1 = bfbits2f(u1), r2 = bfbits2f(u2), r3 = bfbits2f(u3);
    float s = r0 * r0 + r1 * r1 + r2 * r2 + r3 * r3;
    #pragma unroll
    for (int off = 32; off; off >>= 1) s += __shfl_down(s, off);
    if (lane == 0) sq[row] = s;
}

// ---------- kernel B: column sums of G (double) ----------
__global__ __launch_bounds__(256) void k_colsum(const unsigned short* __restrict__ G,
                                                double* __restrict__ colsum) {
    int t  = threadIdx.x;          // column 0..255
    int r0 = blockIdx.x * 128;     // 64 blocks x 128 rows -> 64-deep atomics
    double s = 0.0;
    for (int r = r0; r < r0 + 128; ++r)
        s += (double)bfbits2f(G[(size_t)r * DIM + t]);
    atomicAdd(&colsum[t], s);
}

// ---------- kernel C: bandwidth -> neg_gamma2 = -log2(e)/(16*bw) ----------
__global__ __launch_bounds__(256) void k_bw(const float* __restrict__ sq,
                                            double* __restrict__ wsd) {
    __shared__ double red[256];
    __shared__ double red2[256];
    int t = threadIdx.x;
    double s = 0.0;
    for (int i = t; i < NROW; i += 256) s += (double)sq[i];
    double c = wsd[WS_D_COLSUM + t];
    red[t]  = s;
    red2[t] = c * c;
    __syncthreads();
    for (int off = 128; off; off >>= 1) {
        if (t < off) { red[t] += red[t + off]; red2[t] += red2[t + off]; }
        __syncthreads();
    }
    if (t == 0) {
        const double N = (double)NROW;
        double sum_l2 = 2.0 * N * red[0] - 2.0 * red2[0];
        double bw = sum_l2 / (N * N - N);
        bw = bw / 4.0;  // KERNEL_MUL ** (KERNEL_NUM//2) = 2^2
        wsd[WS_D_NEGG] = -1.4426950408889634 / (16.0 * bw);  // exp2 scaling
    }
}

// ---------- kernel D: MFMA pairwise pass (upper-triangular block tiles) ----------
// LDS: [row][k] bf16, KC=64 (128 B/row = 8 slots of 16 B).
// Physical slot p at row r holds logical slot p ^ (r&7): conflict-free b128
// reads (2-way max) AND linear global_load_lds dest (source is pre-swizzled
// with the same XOR involution -> rule #21 satisfied).
__global__ __launch_bounds__(256) void k_mmd(const unsigned short* __restrict__ G,
                                             const float* __restrict__ sq,
                                             const double* __restrict__ wsd,
                                             double* __restrict__ acc_slots) {
    __shared__ unsigned short As[TILE * KC];   // 16 KB
    __shared__ unsigned short Bs[TILE * KC];   // 16 KB
    __shared__ double wsum[4];

    // decode linear block id -> (bi, bj) with bi <= bj
    int bi = 0, rem = blockIdx.x;
    while (rem >= NB - bi) { rem -= NB - bi; ++bi; }
    int bj = bi + rem;

    int t = threadIdx.x, wid = t >> 6, lane = t & 63;
    int wr = wid >> 1, wc = wid & 1;
    int rl = lane & 15, klane = lane >> 4;

    const unsigned short* Abase = G + (size_t)bi * TILE * DIM;
    const unsigned short* Bbase = G + (size_t)bj * TILE * DIM;

    // staging: wave wid stages tile rows [wid*32, wid*32+32); each of 4 loads
    // covers 8 rows (64 lanes x 16 B / 128 B-row); lane -> row +(l>>3), slot l&7
    int sr8  = (lane >> 3);   // row-within-8
    int sslt = lane & 7;      // physical slot

    const f32x4 zero4 = {0.f, 0.f, 0.f, 0.f};
    f32x4 acc[4][4];
    #pragma unroll
    for (int i = 0; i < 4; ++i)
        #pragma unroll
        for (int j = 0; j < 4; ++j) acc[i][j] = zero4;

    for (int kc = 0; kc < NC; ++kc) {
        __syncthreads();  // previous chunk's ds_reads complete before overwrite
        #pragma unroll
        for (int i = 0; i < 4; ++i) {
            int r    = wid * 32 + i * 8 + sr8;
            int slog = sslt ^ (r & 7);
            gl_lds16(Abase + (size_t)r * DIM + kc * KC + slog * 8,
                     &As[(wid * 32 + i * 8) * KC]);
        }
        #pragma unroll
        for (int i = 0; i < 4; ++i) {
            int r    = wid * 32 + i * 8 + sr8;
            int slog = sslt ^ (r & 7);
            gl_lds16(Bbase + (size_t)r * DIM + kc * KC + slog * 8,
                     &Bs[(wid * 32 + i * 8) * KC]);
        }
        __syncthreads();  // compiler drains vmcnt(0) before barrier -> LDS ready

        #pragma unroll
        for (int ks = 0; ks < 2; ++ks) {
            short8 af[4], bfv[4];
            #pragma unroll
            for (int f = 0; f < 4; ++f) {
                int ra = wr * 64 + f * 16 + rl;
                af[f]  = *(const short8*)&As[ra * KC + ((ks * 4 + klane) ^ (ra & 7)) * 8];
                int rb = wc * 64 + f * 16 + rl;
                bfv[f] = *(const short8*)&Bs[rb * KC + ((ks * 4 + klane) ^ (rb & 7)) * 8];
            }
            #pragma unroll
            for (int i = 0; i < 4; ++i)
                #pragma unroll
                for (int j = 0; j < 4; ++j)
                    acc[i][j] = __builtin_amdgcn_mfma_f32_16x16x32_bf16(af[i], bfv[j], acc[i][j], 0, 0, 0);
        }
    }

    // epilogue: l2 -> 5-kernel sum via exp2-squaring chain
    // C/D layout (m89): col = lane&15, row = (lane>>4)*4 + reg
    int gi0 = bi * TILE + wr * 64;
    int gj0 = bj * TILE + wc * 64;
    float ng2 = (float)wsd[WS_D_NEGG];
    int rgrp = lane >> 4;

    float sqb4[4];
    #pragma unroll
    for (int j = 0; j < 4; ++j) sqb4[j] = sq[gj0 + j * 16 + rl];

    float tsum = 0.f;
    #pragma unroll
    for (int i = 0; i < 4; ++i) {
        float sqa4[4];
        #pragma unroll
        for (int rr = 0; rr < 4; ++rr) sqa4[rr] = sq[gi0 + i * 16 + rgrp * 4 + rr];
        #pragma unroll
        for (int j = 0; j < 4; ++j) {
            #pragma unroll
            for (int rr = 0; rr < 4; ++rr) {
                float l2 = fmaxf(sqa4[rr] + sqb4[j] - 2.0f * acc[i][j][rr], 0.f);
                float e   = exp2f(l2 * ng2);   // exp(-l2/(16 bw)) == kernel i=4
                float e2  = e * e;             // i=3
                float e4  = e2 * e2;           // i=2
                float e8  = e4 * e4;           // i=1
                float e16 = e8 * e8;           // i=0
                tsum += e + e2 + e4 + e8 + e16;
            }
        }
    }

    float w = ((bi < 32) == (bj < 32)) ? 1.f : -1.f;
    if (bi != bj) w *= 2.f;   // off-diagonal tiles count twice (symmetry)
    double dsum = (double)tsum * (double)w;

    #pragma unroll
    for (int off = 32; off; off >>= 1) dsum += __shfl_down(dsum, off);
    if (lane == 0) wsum[wid] = dsum;
    __syncthreads();
    if (t == 0)
        atomicAdd(&acc_slots[blockIdx.x & (WS_ACC_SLOTS - 1)],
                  wsum[0] + wsum[1] + wsum[2] + wsum[3]);
}

// ---------- kernel E: finalize ----------
__global__ void k_final(const double* __restrict__ wsd, float* __restrict__ out) {
    double s = 0.0;
    for (int i = 0; i < WS_ACC_SLOTS; ++i) s += wsd[WS_D_ACC + i];
    out[0] = (float)(s / ((double)HALF * (double)HALF));
}

extern "C" void kernel_launch(void* const* d_in, const int* in_sizes, int n_in,
                              void* d_out, int out_size, void* d_ws, size_t ws_size,
                              hipStream_t stream) {
    const float* src = (const float*)d_in[0];
    const float* tgt = (const float*)d_in[1];
    float* out = (float*)d_out;

    double* wsd         = (double*)d_ws;
    float* sq           = (float*)((char*)d_ws + WS_SQ_OFF);
    unsigned short* G   = (unsigned short*)((char*)d_ws + WS_G_OFF);

    // zero colsum + acc slots (first 4096 B of doubles) every launch
    hipMemsetAsync(d_ws, 0, 4096, stream);

    k_cvt<<<NROW / 4, 256, 0, stream>>>(src, tgt, G, sq);
    k_colsum<<<NROW / 128, 256, 0, stream>>>(G, &wsd[WS_D_COLSUM]);
    k_bw<<<1, 256, 0, stream>>>(sq, wsd);

    int nblocks = NB * (NB + 1) / 2;  // 2080 upper-triangular tiles
    k_mmd<<<nblocks, 256, 0, stream>>>(G, sq, wsd, &wsd[WS_D_ACC]);

    k_final<<<1, 1, 0, stream>>>(wsd, out);
}

// Round 4
// 73.209 us; speedup vs baseline: 4.9659x; 1.0081x over previous
//
#include <hip/hip_runtime.h>
#include <hip/hip_bf16.h>

// MMD loss: source/target 4096x256 fp32, output = scalar fp32.
// N = 8192 rows, D = 256. Pipeline:
//   k_prep  : fp32 -> bf16 G (4 MB ws) + per-row sq[] (from the SAME bf16
//             values -> diagonal exact) + column sums (f64 atomics, 128-deep).
//   k_bw    : sum(sq), ||colsum||^2 -> neg_gamma2 = -log2(e)/(16*bw).
//   k_mmd   : bf16 MFMA Gram pass, upper-triangular 128x128 tiles,
//             KC=32 chunks, TRIPLE-buffered LDS, depth-2 global_load_lds
//             prefetch, one raw s_barrier + counted vmcnt(4) per chunk
//             (load latency hides under MFMA; prefetch never drained).
//   k_final : scale.
//
// ws: doubles d[0..255]=colsum, d[256]=neg_gamma2, d[257..288]=acc slots;
//     float sq[8192] at byte 4096; bf16 G[8192*256] at byte 36864.
#define WS_D_COLSUM 0
#define WS_D_NEGG   256
#define WS_D_ACC    257
#define WS_ACC_SLOTS 32
#define WS_SQ_OFF   4096
#define WS_G_OFF    36864

#define NROW 8192
#define HALF 4096
#define DIM  256
#define TILE 128
#define NB   64            // 8192/128
#define KC   32            // k-chunk (bf16 elems, 64 B/row)
#define NC   (DIM / KC)    // 8 chunks
#define BUFE (TILE * KC)   // 4096 ushorts per buffer

typedef short  short8 __attribute__((ext_vector_type(8)));
typedef float  f32x4  __attribute__((ext_vector_type(4)));
typedef unsigned short us4 __attribute__((ext_vector_type(4)));

static __device__ __forceinline__ unsigned short f2bfbits(float f) {
    __hip_bfloat16 h = __float2bfloat16(f);   // RNE
    return *reinterpret_cast<unsigned short*>(&h);
}
static __device__ __forceinline__ float bfbits2f(unsigned short u) {
    return __uint_as_float(((unsigned int)u) << 16);
}
static __device__ __forceinline__ void gl_lds16(const void* g, void* l) {
    __builtin_amdgcn_global_load_lds(
        (const __attribute__((address_space(1))) void*)g,
        (__attribute__((address_space(3))) void*)l, 16, 0, 0);
}

// ---------- kernel A: cvt + row-sq + colsum partials (fused) ----------
// 128 blocks x 256 threads; block handles 64 rows; wave w handles rows
// r0 + w + 4i (full row per wave per iteration, 64 lanes x 4 cols).
__global__ __launch_bounds__(256) void k_prep(const float* __restrict__ src,
                                              const float* __restrict__ tgt,
                                              unsigned short* __restrict__ G,
                                              float* __restrict__ sq,
                                              double* __restrict__ colsum) {
    __shared__ float cs_lds[4 * 256];
    int t = threadIdx.x, wid = t >> 6, lane = t & 63;
    int r0 = blockIdx.x * 64;
    int c4 = lane * 4;

    float cs0 = 0.f, cs1 = 0.f, cs2 = 0.f, cs3 = 0.f;
    for (int i = 0; i < 16; ++i) {
        int row = r0 + wid + i * 4;
        const float* base = (row < HALF) ? (src + (size_t)row * DIM)
                                         : (tgt + (size_t)(row - HALF) * DIM);
        float4 v = *(const float4*)(base + c4);
        unsigned short u0 = f2bfbits(v.x), u1 = f2bfbits(v.y),
                       u2 = f2bfbits(v.z), u3 = f2bfbits(v.w);
        us4 uu = {u0, u1, u2, u3};
        *(us4*)(G + (size_t)row * DIM + c4) = uu;
        float r0f = bfbits2f(u0), r1f = bfbits2f(u1),
              r2f = bfbits2f(u2), r3f = bfbits2f(u3);
        cs0 += r0f; cs1 += r1f; cs2 += r2f; cs3 += r3f;
        float s = r0f * r0f + r1f * r1f + r2f * r2f + r3f * r3f;
        #pragma unroll
        for (int off = 32; off; off >>= 1) s += __shfl_down(s, off);
        if (lane == 0) sq[row] = s;
    }
    cs_lds[wid * 256 + c4 + 0] = cs0;
    cs_lds[wid * 256 + c4 + 1] = cs1;
    cs_lds[wid * 256 + c4 + 2] = cs2;
    cs_lds[wid * 256 + c4 + 3] = cs3;
    __syncthreads();
    double s = (double)cs_lds[t] + (double)cs_lds[256 + t] +
               (double)cs_lds[512 + t] + (double)cs_lds[768 + t];
    atomicAdd(&colsum[t], s);
}

// ---------- kernel B: bandwidth -> neg_gamma2 = -log2(e)/(16*bw) ----------
__global__ __launch_bounds__(256) void k_bw(const float* __restrict__ sq,
                                            double* __restrict__ wsd) {
    __shared__ double red[256];
    __shared__ double red2[256];
    int t = threadIdx.x;
    double s = 0.0;
    for (int i = t; i < NROW; i += 256) s += (double)sq[i];
    double c = wsd[WS_D_COLSUM + t];
    red[t]  = s;
    red2[t] = c * c;
    __syncthreads();
    for (int off = 128; off; off >>= 1) {
        if (t < off) { red[t] += red[t + off]; red2[t] += red2[t + off]; }
        __syncthreads();
    }
    if (t == 0) {
        const double N = (double)NROW;
        double sum_l2 = 2.0 * N * red[0] - 2.0 * red2[0];
        double bw = sum_l2 / (N * N - N);
        bw = bw / 4.0;  // KERNEL_MUL ** (KERNEL_NUM//2) = 2^2
        wsd[WS_D_NEGG] = -1.4426950408889634 / (16.0 * bw);  // exp2 scaling
    }
}

// ---------- kernel D: MFMA pairwise pass, triple-buffered pipeline ----------
// LDS: [row][k] bf16, KC=32 (64 B/row = 4 slots of 16 B). Physical slot p at
// row r holds logical slot p ^ ((r>>1)&3): b128 frag reads are 2-way max
// (bank = 16*(r&1) + 4*slot + w; each of 8 groups hit exactly twice per
// 16-lane phase) AND staging writes stay linear for global_load_lds
// (source address carries the inverse of the same involution).
__global__ __launch_bounds__(256, 3) void k_mmd(const unsigned short* __restrict__ G,
                                                const float* __restrict__ sq,
                                                const double* __restrict__ wsd,
                                                double* __restrict__ acc_slots) {
    __shared__ unsigned short As[3 * BUFE];   // 24 KB
    __shared__ unsigned short Bs[3 * BUFE];   // 24 KB
    __shared__ double wsum[4];

    // decode linear block id -> (bi, bj) with bi <= bj
    int bi = 0, rem = blockIdx.x;
    while (rem >= NB - bi) { rem -= NB - bi; ++bi; }
    int bj = bi + rem;

    int t = threadIdx.x, wid = t >> 6, lane = t & 63;
    int wr = wid >> 1, wc = wid & 1;
    int rl = lane & 15, klane = lane >> 4;

    const unsigned short* Abase = G + (size_t)bi * TILE * DIM;
    const unsigned short* Bbase = G + (size_t)bj * TILE * DIM;

    // --- precomputed staging geometry (loop-invariant) ---
    // per STAGE: 2 loads per matrix per wave; load i covers 16 rows
    // (lane -> row +(l>>2), physical slot l&3)
    int lr0 = wid * 32 + (lane >> 2);            // local row for i=0
    int slog0 = (lane & 3) ^ ((lr0 >> 1) & 3);
    int lr1 = lr0 + 16;
    int slog1 = (lane & 3) ^ ((lr1 >> 1) & 3);
    size_t ga0 = (size_t)lr0 * DIM + slog0 * 8;  // + kc*KC at use
    size_t ga1 = (size_t)lr1 * DIM + slog1 * 8;
    int ld0 = (wid * 32) * KC;                   // LDS ushort offset, i=0
    int ld1 = (wid * 32 + 16) * KC;

    // --- precomputed fragment-read offsets (loop-invariant) ---
    int aoff[4], boff[4];
    #pragma unroll
    for (int f = 0; f < 4; ++f) {
        int ra = wr * 64 + f * 16 + rl;
        aoff[f] = ra * KC + ((klane ^ ((ra >> 1) & 3)) * 8);
        int rb = wc * 64 + f * 16 + rl;
        boff[f] = rb * KC + ((klane ^ ((rb >> 1) & 3)) * 8);
    }

    const f32x4 zero4 = {0.f, 0.f, 0.f, 0.f};
    f32x4 acc[4][4];
    #pragma unroll
    for (int i = 0; i < 4; ++i)
        #pragma unroll
        for (int j = 0; j < 4; ++j) acc[i][j] = zero4;

    #define STAGE(kc, b)                                                     \
        do {                                                                 \
            gl_lds16(Abase + ga0 + (kc) * KC, &As[(b) * BUFE + ld0]);        \
            gl_lds16(Bbase + ga0 + (kc) * KC, &Bs[(b) * BUFE + ld0]);        \
            gl_lds16(Abase + ga1 + (kc) * KC, &As[(b) * BUFE + ld1]);        \
            gl_lds16(Bbase + ga1 + (kc) * KC, &Bs[(b) * BUFE + ld1]);        \
        } while (0)

    // prologue: prefetch chunks 0 and 1
    STAGE(0, 0);
    STAGE(1, 1);

    #pragma unroll
    for (int kc = 0; kc < NC; ++kc) {
        // wait for chunk kc's 4 loads (oldest); keep chunk kc+1's in flight
        if (kc < NC - 1) { asm volatile("s_waitcnt vmcnt(4)" ::: "memory"); }
        else             { asm volatile("s_waitcnt vmcnt(0)" ::: "memory"); }
        __builtin_amdgcn_s_barrier();
        __builtin_amdgcn_sched_barrier(0);
        if (kc + 2 < NC) STAGE(kc + 2, (kc + 2) % 3);

        const unsigned short* Ab = &As[(kc % 3) * BUFE];
        const unsigned short* Bb = &Bs[(kc % 3) * BUFE];
        short8 af[4], bfv[4];
        #pragma unroll
        for (int f = 0; f < 4; ++f) {
            af[f]  = *(const short8*)&Ab[aoff[f]];
            bfv[f] = *(const short8*)&Bb[boff[f]];
        }
        #pragma unroll
        for (int i = 0; i < 4; ++i)
            #pragma unroll
            for (int j = 0; j < 4; ++j)
                acc[i][j] = __builtin_amdgcn_mfma_f32_16x16x32_bf16(af[i], bfv[j], acc[i][j], 0, 0, 0);
    }
    #undef STAGE

    // epilogue: l2 -> 5-kernel sum via exp2-squaring chain
    // C/D layout (m89): col = lane&15, row = (lane>>4)*4 + reg
    int gi0 = bi * TILE + wr * 64;
    int gj0 = bj * TILE + wc * 64;
    float ng2 = (float)wsd[WS_D_NEGG];
    int rgrp = lane >> 4;

    float sqb4[4];
    #pragma unroll
    for (int j = 0; j < 4; ++j) sqb4[j] = sq[gj0 + j * 16 + rl];

    float tsum = 0.f;
    #pragma unroll
    for (int i = 0; i < 4; ++i) {
        float sqa4[4];
        #pragma unroll
        for (int rr = 0; rr < 4; ++rr) sqa4[rr] = sq[gi0 + i * 16 + rgrp * 4 + rr];
        #pragma unroll
        for (int j = 0; j < 4; ++j) {
            #pragma unroll
            for (int rr = 0; rr < 4; ++rr) {
                float l2 = fmaxf(sqa4[rr] + sqb4[j] - 2.0f * acc[i][j][rr], 0.f);
                float e   = exp2f(l2 * ng2);   // exp(-l2/(16 bw)) == kernel i=4
                float e2  = e * e;             // i=3
                float e4  = e2 * e2;           // i=2
                float e8  = e4 * e4;           // i=1
                float e16 = e8 * e8;           // i=0
                tsum += e + e2 + e4 + e8 + e16;
            }
        }
    }

    float w = ((bi < 32) == (bj < 32)) ? 1.f : -1.f;
    if (bi != bj) w *= 2.f;   // off-diagonal tiles count twice (symmetry)
    double dsum = (double)tsum * (double)w;

    #pragma unroll
    for (int off = 32; off; off >>= 1) dsum += __shfl_down(dsum, off);
    if (lane == 0) wsum[wid] = dsum;
    __syncthreads();
    if (t == 0)
        atomicAdd(&acc_slots[blockIdx.x & (WS_ACC_SLOTS - 1)],
                  wsum[0] + wsum[1] + wsum[2] + wsum[3]);
}

// ---------- kernel E: finalize ----------
__global__ void k_final(const double* __restrict__ wsd, float* __restrict__ out) {
    double s = 0.0;
    for (int i = 0; i < WS_ACC_SLOTS; ++i) s += wsd[WS_D_ACC + i];
    out[0] = (float)(s / ((double)HALF * (double)HALF));
}

extern "C" void kernel_launch(void* const* d_in, const int* in_sizes, int n_in,
                              void* d_out, int out_size, void* d_ws, size_t ws_size,
                              hipStream_t stream) {
    const float* src = (const float*)d_in[0];
    const float* tgt = (const float*)d_in[1];
    float* out = (float*)d_out;

    double* wsd       = (double*)d_ws;
    float* sq         = (float*)((char*)d_ws + WS_SQ_OFF);
    unsigned short* G = (unsigned short*)((char*)d_ws + WS_G_OFF);

    // zero colsum + negg + acc slots every launch
    hipMemsetAsync(d_ws, 0, 4096, stream);

    k_prep<<<128, 256, 0, stream>>>(src, tgt, G, sq, &wsd[WS_D_COLSUM]);
    k_bw<<<1, 256, 0, stream>>>(sq, wsd);

    int nblocks = NB * (NB + 1) / 2;  // 2080 upper-triangular tiles
    k_mmd<<<nblocks, 256, 0, stream>>>(G, sq, wsd, &wsd[WS_D_ACC]);

    k_final<<<1, 1, 0, stream>>>(wsd, out);
}